// Round 5
// baseline (2505.511 us; speedup 1.0000x reference)
//
#include <hip/hip_runtime.h>
#include <hip/hip_bf16.h>

#define NB 32      // batch
#define NS 256     // seq len
#define NI 1024    // input size
#define NO 1024    // hidden size
#define NK 2048    // NI + NO
#define NC 4096    // 4 * NO
#define LN_EPS 1e-5f

typedef __attribute__((ext_vector_type(4))) float f32x4;
typedef __attribute__((ext_vector_type(4))) unsigned int u32x4;

__device__ __forceinline__ f32x4 mfma_bf16_16x16x32(u32x4 a, u32x4 b, f32x4 c) {
  asm volatile("v_mfma_f32_16x16x32_bf16 %0, %1, %2, %0" : "+v"(c) : "v"(a), "v"(b));
  return c;
}

__device__ __forceinline__ float sigf(float x) { return 1.0f / (1.0f + __expf(-x)); }
// tanh(x) = 1 - 2/(e^{2x}+1); overflow -> 1, underflow -> -1. Both correct.
__device__ __forceinline__ float tanhfast(float x) {
  return 1.0f - 2.0f / (__expf(2.0f * x) + 1.0f);
}

// ---------------- setup kernels ----------------

// x fp32 [m][t][k] -> xfrag bf16 in MFMA A-fragment order:
// xfrag[((t*32 + kt)*2 + plane)*512 + l*8 + j] = x[m=plane*16+(l&15)][t][kt*32+(l>>4)*8+j]
__global__ void pack_x(const float* __restrict__ x, __hip_bfloat16* __restrict__ xfrag) {
  const int t = blockIdx.x, kt = blockIdx.y;
  const int tid = threadIdx.x;
  const int plane = tid >> 6, l = tid & 63, q = (l >> 4), ln = l & 15;
  const int m = plane * 16 + ln;
  const float* src = x + ((size_t)m * NS + t) * NI + kt * 32 + q * 8;
  float4 v0 = *(const float4*)src;
  float4 v1 = *(const float4*)(src + 4);
  __align__(16) __hip_bfloat16 tmp[8];
  tmp[0] = __float2bfloat16(v0.x); tmp[1] = __float2bfloat16(v0.y);
  tmp[2] = __float2bfloat16(v0.z); tmp[3] = __float2bfloat16(v0.w);
  tmp[4] = __float2bfloat16(v1.x); tmp[5] = __float2bfloat16(v1.y);
  tmp[6] = __float2bfloat16(v1.z); tmp[7] = __float2bfloat16(v1.w);
  *(u32x4*)(xfrag + (((size_t)t * 32 + kt) * 2 + plane) * 512 + l * 8) = *(const u32x4*)tmp;
}

// W fp32 [k=2048][n=4096] -> WF bf16 in MFMA-fragment order.
// b-group bg owns cols n(c) = (c>>2)*1024 + bg*4 + (c&3), c = lane&15.
__global__ void pack_wf(const float* __restrict__ W, __hip_bfloat16* __restrict__ WF) {
  const int blk = blockIdx.x;
  const int b = blk >> 6, kt = blk & 63;
  const int l = threadIdx.x, q = l >> 4, c = l & 15;
  const int n  = ((c >> 2) << 10) + b * 4 + (c & 3);
  const int k0 = kt * 32 + q * 8;
  __align__(16) __hip_bfloat16 tmp[8];
#pragma unroll
  for (int j = 0; j < 8; ++j)
    tmp[j] = __float2bfloat16(W[(size_t)(k0 + j) * NC + n]);
  *(u32x4*)(WF + ((size_t)(b * 64 + kt) * 64 + l) * 8) = *(const u32x4*)tmp;
}

// hfrag index for h[m][j] (A-fragment order, 2 planes of 16 rows):
__device__ __forceinline__ size_t hfrag_idx(int m, int j) {
  const int kt = j >> 5, q = (j >> 3) & 3, jj = j & 7;
  const int plane = m >> 4, l = q * 16 + (m & 15);
  return (((size_t)kt * 2 + plane) * 64 + l) * 8 + jj;
}

__global__ void init_state(const float* __restrict__ hx0, const float* __restrict__ cx0,
                           __hip_bfloat16* __restrict__ hfrag, float* __restrict__ cst,
                           float* __restrict__ hf) {
  const int i = blockIdx.x * 256 + threadIdx.x;  // 32768 = NB*NO
  const int m = i >> 10, j = i & (NO - 1);
  const float hv = hx0[j];
  hfrag[hfrag_idx(m, j)] = __float2bfloat16(hv);
  hf[i]  = hv;
  cst[i] = cx0[j];
}

// ---------------- one-shot GEMM: xw[t][m][n] = bias[n] + x_t @ Wx ----------------
// grid (64 t-quads, 32 nb) x 512 thr. Wave w: tp=w>>2 (t-pair), ng=w&3 (2 b-groups).
// acc[tt][plane][g]; all frags streamed from L2 (contiguous 16B/lane).
__global__ __launch_bounds__(512)
void precompute_xw(const __hip_bfloat16* __restrict__ xfrag,
                   const __hip_bfloat16* __restrict__ WF,
                   const float* __restrict__ bias,
                   float* __restrict__ xw) {
  const int tq = blockIdx.x, nb = blockIdx.y;
  const int tid = threadIdx.x;
  const int w = tid >> 6, l = tid & 63, q = l >> 4, c = l & 15;
  const int tp = w >> 2, ng = w & 3;
  const int t0  = tq * 4 + tp * 2;
  const int bg0 = nb * 8 + ng * 2;

  float bias_g[2];
#pragma unroll
  for (int g = 0; g < 2; ++g)
    bias_g[g] = bias[((c >> 2) << 10) + (bg0 + g) * 4 + (c & 3)];

  f32x4 acc[2][2][2] = {};   // [tt][plane][g]
  asm volatile("s_nop 1" ::);
  for (int kt = 0; kt < 32; ++kt) {
    u32x4 a[2][2], bb[2];
#pragma unroll
    for (int tt = 0; tt < 2; ++tt)
#pragma unroll
      for (int p = 0; p < 2; ++p)
        a[tt][p] = *(const u32x4*)(xfrag +
            (((size_t)(t0 + tt) * 32 + kt) * 2 + p) * 512 + l * 8);
#pragma unroll
    for (int g = 0; g < 2; ++g)
      bb[g] = *(const u32x4*)(WF + (((size_t)(bg0 + g) * 64 + kt) * 64 + l) * 8);
#pragma unroll
    for (int tt = 0; tt < 2; ++tt)
#pragma unroll
      for (int p = 0; p < 2; ++p)
#pragma unroll
        for (int g = 0; g < 2; ++g)
          acc[tt][p][g] = mfma_bf16_16x16x32(a[tt][p], bb[g], acc[tt][p][g]);
  }
  asm volatile("s_nop 7\n\ts_nop 7" ::);
#pragma unroll
  for (int tt = 0; tt < 2; ++tt)
#pragma unroll
    for (int p = 0; p < 2; ++p)
#pragma unroll
      for (int g = 0; g < 2; ++g) {
        const int n = ((c >> 2) << 10) + (bg0 + g) * 4 + (c & 3);
#pragma unroll
        for (int r = 0; r < 4; ++r) {
          const int row = p * 16 + q * 4 + r;
          xw[((size_t)(t0 + tt) * 32 + row) * NC + n] = acc[tt][p][g][r] + bias_g[g];
        }
      }
}

// ---------------- per-step kernel A: h-GEMM (K=1024) ----------------
// grid 256 x 512 (8 waves). Block b owns 16 interleaved n-cols. Wave w:
// plane p=w&1, K-slice kt in [(w>>1)*8, +8) of the h-part (global kt 32+..).
// Epilogue: reduce 4 K-partials per plane via LDS, add xw, write comb.
__global__ __launch_bounds__(512)
void step_gemm_h(const __hip_bfloat16* __restrict__ hfrag,
                 const __hip_bfloat16* __restrict__ WF,
                 const float* __restrict__ xw,
                 float* __restrict__ comb, int t) {
  __shared__ __align__(16) float xch[8 * 256];   // 8KB
  const int b = blockIdx.x, tid = threadIdx.x;
  const int w = tid >> 6, l = tid & 63;
  const int p = w & 1, k0 = (w >> 1) * 8;

  const __hip_bfloat16* ap = hfrag + ((size_t)k0 * 2 + p) * 512 + l * 8;
  const __hip_bfloat16* bp = WF + (((size_t)b * 64 + 32 + k0) * 64 + l) * 8;

  f32x4 acc = {0.f, 0.f, 0.f, 0.f};
  asm volatile("s_nop 1" ::);  // VALU-write(acc init) -> MFMA-read-C hazard
#pragma unroll
  for (int i = 0; i < 8; ++i) {
    u32x4 a  = *(const u32x4*)(ap + (size_t)i * 1024);
    u32x4 bb = *(const u32x4*)(bp + (size_t)i * 512);
    acc = mfma_bf16_16x16x32(a, bb, acc);
  }
  asm volatile("s_nop 7\n\ts_nop 7" ::);  // MFMA-write -> VALU-read hazard

  *(f32x4*)(xch + w * 256 + l * 4) = acc;
  __syncthreads();

  const int row = tid >> 4, c = tid & 15;
  const int pp = row >> 4, rr = row & 15;
  const int idx = ((rr >> 2) * 16 + c) * 4 + (rr & 3);
  const int n = ((c >> 2) << 10) + b * 4 + (c & 3);
  float v = xw[((size_t)t * 32 + row) * NC + n];   // bias already folded in
#pragma unroll
  for (int i = 0; i < 4; ++i) v += xch[(i * 2 + pp) * 256 + idx];
  comb[(size_t)row * NC + n] = v;
}

// ---------------- mid-tier per-step GEMM (round-4, K=2048) ----------------
__global__ __launch_bounds__(512)
void step_gemm_mfma(const __hip_bfloat16* __restrict__ xfrag,
                    const __hip_bfloat16* __restrict__ hfrag,
                    const __hip_bfloat16* __restrict__ WF,
                    const float* __restrict__ bias,
                    float* __restrict__ comb, int t) {
  __shared__ __align__(16) float xch[8 * 2 * 256];   // 16KB
  const int b = blockIdx.x, tid = threadIdx.x;
  const int wv = tid >> 6, l = tid & 63;

  const __hip_bfloat16* ap = (wv < 4)
      ? xfrag + ((size_t)t * 32 + wv * 8) * 1024 + l * 8
      : hfrag + ((size_t)(wv - 4) * 8) * 1024 + l * 8;
  const __hip_bfloat16* bp = WF + ((size_t)(b * 64 + wv * 8) * 64 + l) * 8;

  f32x4 acc0 = {0.f, 0.f, 0.f, 0.f}, acc1 = {0.f, 0.f, 0.f, 0.f};
  asm volatile("s_nop 1" ::);
#pragma unroll
  for (int i = 0; i < 8; ++i) {
    u32x4 a0 = *(const u32x4*)(ap + (size_t)i * 1024);
    u32x4 a1 = *(const u32x4*)(ap + (size_t)i * 1024 + 512);
    u32x4 bb = *(const u32x4*)(bp + (size_t)i * 512);
    acc0 = mfma_bf16_16x16x32(a0, bb, acc0);
    acc1 = mfma_bf16_16x16x32(a1, bb, acc1);
  }
  asm volatile("s_nop 7\n\ts_nop 7" ::);

  *(f32x4*)(xch + (wv * 2 + 0) * 256 + l * 4) = acc0;
  *(f32x4*)(xch + (wv * 2 + 1) * 256 + l * 4) = acc1;
  __syncthreads();

  const int row = tid >> 4, c = tid & 15;
  const int p = row >> 4, rr = row & 15;
  const int idx = ((rr >> 2) * 16 + c) * 4 + (rr & 3);
  const int n = ((c >> 2) << 10) + b * 4 + (c & 3);
  float v = bias[n];
#pragma unroll
  for (int w = 0; w < 8; ++w) v += xch[(w * 2 + p) * 256 + idx];
  comb[(size_t)row * NC + n] = v;
}

// ---------------- per-step kernel B: LN + gates + state ----------------
__global__ __launch_bounds__(1024)
void step_update_row(const float* __restrict__ comb,
                     const float* __restrict__ gamma,
                     const float* __restrict__ beta,
                     float* __restrict__ cst,
                     float* __restrict__ out,
                     __hip_bfloat16* __restrict__ hfrag,
                     int t) {
  __shared__ __align__(16) float combL[NC];
  __shared__ float red[16][2];
  __shared__ float stat[2];
  const int m = blockIdx.x, tid = threadIdx.x;

  f32x4 cv = *(const f32x4*)(comb + (size_t)m * NC + tid * 4);
  *(f32x4*)(combL + tid * 4) = cv;
  float s  = cv[0] + cv[1] + cv[2] + cv[3];
  float ss = cv[0] * cv[0] + cv[1] * cv[1] + cv[2] * cv[2] + cv[3] * cv[3];
#pragma unroll
  for (int off = 1; off < 64; off <<= 1) {
    s  += __shfl_xor(s, off);
    ss += __shfl_xor(ss, off);
  }
  const int wid = tid >> 6;
  if ((tid & 63) == 0) { red[wid][0] = s; red[wid][1] = ss; }
  __syncthreads();
  if (tid == 0) {
    float s2 = 0.f, ss2 = 0.f;
#pragma unroll
    for (int i = 0; i < 16; ++i) { s2 += red[i][0]; ss2 += red[i][1]; }
    const float mean = s2 * (1.f / NC);
    const float var  = ss2 * (1.f / NC) - mean * mean;
    stat[0] = mean;
    stat[1] = rsqrtf(var + LN_EPS);
  }
  __syncthreads();
  const float mean = stat[0], rs = stat[1];
  const int j = tid;
  const float iv = (combL[j]          - mean) * rs * gamma[j]          + beta[j];
  const float fv = (combL[NO + j]     - mean) * rs * gamma[NO + j]     + beta[NO + j];
  const float gv = (combL[2 * NO + j] - mean) * rs * gamma[2 * NO + j] + beta[2 * NO + j];
  const float ov = (combL[3 * NO + j] - mean) * rs * gamma[3 * NO + j] + beta[3 * NO + j];
  const float cold = cst[(size_t)m * NO + j];
  const float cc = sigf(fv) * cold + sigf(iv) * tanhfast(gv);
  const float hh = sigf(ov) * cc;
  cst[(size_t)m * NO + j] = cc;
  out[((size_t)m * NS + t) * NO + j] = hh;
  hfrag[hfrag_idx(m, j)] = __float2bfloat16(hh);
}

// ---------------- bottom-tier fp32 path ----------------

__launch_bounds__(256)
__global__ void step_gemm_f32(const float* __restrict__ x, const float* __restrict__ hf,
                              const float* __restrict__ W, const float* __restrict__ bias,
                              float* __restrict__ comb, int t) {
  const int blk = blockIdx.x;
  const int tid = threadIdx.x;
  const int n   = blk * 16 + (tid & 15);
  const int mlo = tid >> 4;
  float a0 = 0.f, a1 = 0.f;
  for (int k = 0; k < NI; ++k) {
    const float wv = W[(size_t)k * NC + n];
    a0 += x[((size_t)mlo * NS + t) * NI + k] * wv;
    a1 += x[((size_t)(mlo + 16) * NS + t) * NI + k] * wv;
  }
  for (int k = 0; k < NO; ++k) {
    const float wv = W[(size_t)(NI + k) * NC + n];
    a0 += hf[mlo * NO + k] * wv;
    a1 += hf[(mlo + 16) * NO + k] * wv;
  }
  comb[(size_t)mlo * NC + n] = a0 + bias[n];
  comb[(size_t)(mlo + 16) * NC + n] = a1 + bias[n];
}

__global__ __launch_bounds__(1024)
void step_update_row_f32(const float* __restrict__ comb,
                         const float* __restrict__ gamma,
                         const float* __restrict__ beta,
                         float* __restrict__ cst,
                         float* __restrict__ out,
                         float* __restrict__ hf,
                         int t) {
  __shared__ __align__(16) float combL[NC];
  __shared__ float red[16][2];
  __shared__ float stat[2];
  const int m = blockIdx.x, tid = threadIdx.x;
  f32x4 cv = *(const f32x4*)(comb + (size_t)m * NC + tid * 4);
  *(f32x4*)(combL + tid * 4) = cv;
  float s  = cv[0] + cv[1] + cv[2] + cv[3];
  float ss = cv[0] * cv[0] + cv[1] * cv[1] + cv[2] * cv[2] + cv[3] * cv[3];
#pragma unroll
  for (int off = 1; off < 64; off <<= 1) {
    s  += __shfl_xor(s, off);
    ss += __shfl_xor(ss, off);
  }
  const int wid = tid >> 6;
  if ((tid & 63) == 0) { red[wid][0] = s; red[wid][1] = ss; }
  __syncthreads();
  if (tid == 0) {
    float s2 = 0.f, ss2 = 0.f;
    for (int i = 0; i < 16; ++i) { s2 += red[i][0]; ss2 += red[i][1]; }
    const float mean = s2 * (1.f / NC);
    const float var  = ss2 * (1.f / NC) - mean * mean;
    stat[0] = mean;
    stat[1] = rsqrtf(var + LN_EPS);
  }
  __syncthreads();
  const float mean = stat[0], rs = stat[1];
  const int j = tid;
  const float iv = (combL[j]          - mean) * rs * gamma[j]          + beta[j];
  const float fv = (combL[NO + j]     - mean) * rs * gamma[NO + j]     + beta[NO + j];
  const float gv = (combL[2 * NO + j] - mean) * rs * gamma[2 * NO + j] + beta[2 * NO + j];
  const float ov = (combL[3 * NO + j] - mean) * rs * gamma[3 * NO + j] + beta[3 * NO + j];
  const float cold = cst[(size_t)m * NO + j];
  const float cc = sigf(fv) * cold + sigf(iv) * tanhfast(gv);
  const float hh = sigf(ov) * cc;
  cst[(size_t)m * NO + j] = cc;
  out[((size_t)m * NS + t) * NO + j] = hh;
  hf[(size_t)m * NO + j] = hh;
}

// ---------------- launch ----------------

extern "C" void kernel_launch(void* const* d_in, const int* in_sizes, int n_in,
                              void* d_out, int out_size, void* d_ws, size_t ws_size,
                              hipStream_t stream) {
  (void)in_sizes; (void)n_in; (void)out_size;
  const float* x     = (const float*)d_in[0];
  const float* W     = (const float*)d_in[1];
  const float* bias  = (const float*)d_in[2];
  const float* gamma = (const float*)d_in[3];
  const float* beta  = (const float*)d_in[4];
  const float* hx0   = (const float*)d_in[5];
  const float* cx0   = (const float*)d_in[6];
  float* outp = (float*)d_out;

  char* ws = (char*)d_ws;
  size_t off = 0;
  auto alloc = [&](size_t bytes) -> char* {
    off = (off + 255) & ~(size_t)255;
    char* p = ws + off;
    off += bytes;
    return p;
  };
  // small (all tiers)
  float* comb           = (float*)alloc((size_t)NB * NC * 4);            // 512KB
  float* cst            = (float*)alloc((size_t)NB * NO * 4);            // 128KB
  float* hf             = (float*)alloc((size_t)NB * NO * 4);            // 128KB
  __hip_bfloat16* hfrag = (__hip_bfloat16*)alloc((size_t)NB * NO * 2);   // 64KB
  // mid tier
  __hip_bfloat16* xfrag = (__hip_bfloat16*)alloc((size_t)NB * NS * NI * 2);  // 16.8MB
  __hip_bfloat16* WF    = (__hip_bfloat16*)alloc((size_t)NK * NC * 2);       // 16.8MB
  const size_t off_mid = off;
  // full tier
  float* xw             = (float*)alloc((size_t)NS * NB * NC * 4);       // 134.2MB
  const size_t off_full = off;
  const int tier = (ws_size >= off_full) ? 2 : (ws_size >= off_mid) ? 1 : 0;

  hipLaunchKernelGGL(init_state, dim3((NB * NO) / 256), dim3(256), 0, stream,
                     hx0, cx0, hfrag, cst, hf);
  if (tier == 2) {
    hipLaunchKernelGGL(pack_x, dim3(NS, 32), dim3(128), 0, stream, x, xfrag);
    hipLaunchKernelGGL(pack_wf, dim3(256 * 64), dim3(64), 0, stream, W, WF);
    hipLaunchKernelGGL(precompute_xw, dim3(64, 32), dim3(512), 0, stream,
                       xfrag, WF, bias, xw);
    for (int t = 0; t < NS; ++t) {
      hipLaunchKernelGGL(step_gemm_h, dim3(256), dim3(512), 0, stream,
                         hfrag, WF, xw, comb, t);
      hipLaunchKernelGGL(step_update_row, dim3(NB), dim3(1024), 0, stream,
                         comb, gamma, beta, cst, outp, hfrag, t);
    }
  } else if (tier == 1) {
    hipLaunchKernelGGL(pack_x, dim3(NS, 32), dim3(128), 0, stream, x, xfrag);
    hipLaunchKernelGGL(pack_wf, dim3(256 * 64), dim3(64), 0, stream, W, WF);
    for (int t = 0; t < NS; ++t) {
      hipLaunchKernelGGL(step_gemm_mfma, dim3(256), dim3(512), 0, stream,
                         xfrag, hfrag, WF, bias, comb, t);
      hipLaunchKernelGGL(step_update_row, dim3(NB), dim3(1024), 0, stream,
                         comb, gamma, beta, cst, outp, hfrag, t);
    }
  } else {
    for (int t = 0; t < NS; ++t) {
      hipLaunchKernelGGL(step_gemm_f32, dim3(256), dim3(256), 0, stream,
                         x, hf, W, bias, comb, t);
      hipLaunchKernelGGL(step_update_row_f32, dim3(NB), dim3(1024), 0, stream,
                         comb, gamma, beta, cst, outp, hf, t);
    }
  }
}